// Round 3
// baseline (279.721 us; speedup 1.0000x reference)
//
#include <hip/hip_runtime.h>
#include <math.h>

// BatchedCauchyKernel3d: out[b,i,j] = 1 / (1 + d/sqrt(scx[b,i]*scy[b,j]))
// d = clip(|x_i|^2 + |y_j|^2 - 2 x_i.y_j, 1e-10, 1e6)
// scx = clip(sample_x . clip(scale,1e-6,1e6), 1e-10, 1e6); likewise scy.
// Identities used:
//   1/(1+d/s) == s/(s+d)                  -> one rcp per element
//   sqrt(clip(scx*scy)) ~= sqrt(scx)*sqrt(scy)  (clip binds only when
//       product < 1e-10; error < 1e-3 there, vs 2e-2 threshold)
// so the prepass stores (|p|^2, sqrt(clipped scale-dot)) per point and the
// 67M-element inner loop is 1 fma-dot + 1 clamp + 1 mul + 1 rcp + 1 mul.

constexpr int kB  = 4;
constexpr int kNX = 4096;
constexpr int kNY = 4096;
constexpr int kF  = 16;

typedef float f32x4 __attribute__((ext_vector_type(4)));  // native vec for nt-store

// ---------------- pre-pass: per-point (|p|^2, sqrt(clipped scale-dot)) ------
__global__ __launch_bounds__(256) void row_stats_kernel(
    const float* __restrict__ x, const float* __restrict__ y,
    const float* __restrict__ sx, const float* __restrict__ sy,
    const float* __restrict__ scale,
    float2* __restrict__ rx, float2* __restrict__ ry, int nper)
{
    int t = blockIdx.x * blockDim.x + threadIdx.x;
    if (t >= 2 * nper) return;
    const float* pts; const float* smp; float2* dst; int idx;
    if (t < nper) { pts = x; smp = sx; dst = rx; idx = t; }
    else          { pts = y; smp = sy; dst = ry; idx = t - nper; }

    const float* p = pts + (size_t)idx * 3;
    float sq = p[0] * p[0] + p[1] * p[1] + p[2] * p[2];

    const float4* s4 = (const float4*)(smp + (size_t)idx * kF);
    const float4* c4 = (const float4*)scale;
    float acc = 0.f;
#pragma unroll
    for (int k = 0; k < kF / 4; ++k) {
        float4 sv = s4[k];
        float4 cv = c4[k];
        acc += sv.x * fminf(fmaxf(cv.x, 1e-6f), 1e6f);
        acc += sv.y * fminf(fmaxf(cv.y, 1e-6f), 1e6f);
        acc += sv.z * fminf(fmaxf(cv.z, 1e-6f), 1e6f);
        acc += sv.w * fminf(fmaxf(cv.w, 1e-6f), 1e6f);
    }
    float sc = fminf(fmaxf(acc, 1e-10f), 1e6f);
    dst[idx] = make_float2(sq, sqrtf(sc));
}

// ---------------- main: 8 rows x 4 cols per thread --------------------------
// thread t -> jc = t & 1023 (j0 = 4*jc), rowtile = t >> 10
// (i0 = 8*(rowtile & 511), b = rowtile >> 9). Stores 8x float4; within a
// wave, lanes have consecutive jc -> each store instr covers a contiguous
// 1 KiB. Nontemporal: output is stream-once, keep L2 for y-side reuse.
__global__ __launch_bounds__(256) void cauchy_main_kernel(
    const float* __restrict__ x, const float2* __restrict__ rx,
    const float* __restrict__ y, const float2* __restrict__ ry,
    float* __restrict__ out)
{
    const int t = blockIdx.x * 256 + threadIdx.x;
    const int jc = t & (kNY / 4 - 1);
    const int rowtile = t >> 10;
    const int b  = rowtile >> 9;
    const int i0 = (rowtile & (kNX / 8 - 1)) * 8;
    const int j0 = jc * 4;

    // y side: 4 points = 12 contiguous floats (16B aligned) + 4 float2 stats
    float yco[12];
    const float4* yv = (const float4*)(y + ((size_t)b * kNY + j0) * 3);
#pragma unroll
    for (int k = 0; k < 3; ++k) *(float4*)(yco + 4 * k) = yv[k];
    float2 rys[4];
    const float4* ryv = (const float4*)(ry + (size_t)b * kNY + j0);
    *(float4*)(&rys[0]) = ryv[0];
    *(float4*)(&rys[2]) = ryv[1];

    // x side: 8 points = 24 floats + 8 float2 stats (broadcast across the
    // 1024 threads sharing this rowtile -> L1 hits)
    float xco[24];
    const float4* xv = (const float4*)(x + ((size_t)b * kNX + i0) * 3);
#pragma unroll
    for (int k = 0; k < 6; ++k) *(float4*)(xco + 4 * k) = xv[k];
    float2 rxs[8];
    const float4* rxv = (const float4*)(rx + (size_t)b * kNX + i0);
#pragma unroll
    for (int k = 0; k < 4; ++k) *(float4*)(&rxs[2 * k]) = rxv[k];

    const size_t obase = ((size_t)b * kNX + i0) * (size_t)kNY + j0;
#pragma unroll
    for (int r = 0; r < 8; ++r) {
        const float px = xco[3 * r], py = xco[3 * r + 1], pz = xco[3 * r + 2];
        const float sqx = rxs[r].x, rsx = rxs[r].y;
        f32x4 o;
#pragma unroll
        for (int k = 0; k < 4; ++k) {
            float dot = px * yco[3 * k] + py * yco[3 * k + 1] + pz * yco[3 * k + 2];
            float d = fmaf(-2.f, dot, sqx + rys[k].x);
            d = fminf(fmaxf(d, 1e-10f), 1e6f);
            float s = rsx * rys[k].y;
            o[k] = s * __builtin_amdgcn_rcpf(s + d);
        }
        __builtin_nontemporal_store(o, (f32x4*)(out + obase + (size_t)r * kNY));
    }
}

// ---------------- fallback (ws too small): stats inline, 4x4 tile -----------
__global__ __launch_bounds__(256) void cauchy_fallback_kernel(
    const float* __restrict__ x, const float* __restrict__ y,
    const float* __restrict__ sx, const float* __restrict__ sy,
    const float* __restrict__ scale, float* __restrict__ out)
{
    const int t = blockIdx.x * 256 + threadIdx.x;
    const int jc = t & (kNY / 4 - 1);
    const int rowtile = t >> 10;
    const int b  = rowtile >> 10;
    const int i0 = (rowtile & (kNX / 4 - 1)) * 4;
    const int j0 = jc * 4;

    float4 c[4];
    const float4* c4 = (const float4*)scale;
#pragma unroll
    for (int k = 0; k < 4; ++k) {
        float4 cv = c4[k];
        c[k].x = fminf(fmaxf(cv.x, 1e-6f), 1e6f);
        c[k].y = fminf(fmaxf(cv.y, 1e-6f), 1e6f);
        c[k].z = fminf(fmaxf(cv.z, 1e-6f), 1e6f);
        c[k].w = fminf(fmaxf(cv.w, 1e-6f), 1e6f);
    }

    float yco[12], xco[12];
    const float4* yv = (const float4*)(y + ((size_t)b * kNY + j0) * 3);
#pragma unroll
    for (int k = 0; k < 3; ++k) *(float4*)(yco + 4 * k) = yv[k];
    const float4* xv = (const float4*)(x + ((size_t)b * kNX + i0) * 3);
#pragma unroll
    for (int k = 0; k < 3; ++k) *(float4*)(xco + 4 * k) = xv[k];

    float sqx[4], rsx[4], sqy[4], rsy[4];
#pragma unroll
    for (int r = 0; r < 4; ++r) {
        sqx[r] = xco[3*r]*xco[3*r] + xco[3*r+1]*xco[3*r+1] + xco[3*r+2]*xco[3*r+2];
        sqy[r] = yco[3*r]*yco[3*r] + yco[3*r+1]*yco[3*r+1] + yco[3*r+2]*yco[3*r+2];
        const float4* a4 = (const float4*)(sx + ((size_t)b * kNX + i0 + r) * kF);
        const float4* b4 = (const float4*)(sy + ((size_t)b * kNY + j0 + r) * kF);
        float accx = 0.f, accy = 0.f;
#pragma unroll
        for (int k = 0; k < 4; ++k) {
            float4 av = a4[k], bv = b4[k], cv = c[k];
            accx += av.x * cv.x + av.y * cv.y + av.z * cv.z + av.w * cv.w;
            accy += bv.x * cv.x + bv.y * cv.y + bv.z * cv.z + bv.w * cv.w;
        }
        rsx[r] = sqrtf(fminf(fmaxf(accx, 1e-10f), 1e6f));
        rsy[r] = sqrtf(fminf(fmaxf(accy, 1e-10f), 1e6f));
    }

    const size_t obase = ((size_t)b * kNX + i0) * (size_t)kNY + j0;
#pragma unroll
    for (int r = 0; r < 4; ++r) {
        float4 o;
        float* op = (float*)&o;
#pragma unroll
        for (int k = 0; k < 4; ++k) {
            float dot = xco[3*r] * yco[3*k] + xco[3*r+1] * yco[3*k+1]
                      + xco[3*r+2] * yco[3*k+2];
            float d = fmaf(-2.f, dot, sqx[r] + sqy[k]);
            d = fminf(fmaxf(d, 1e-10f), 1e6f);
            float s = rsx[r] * rsy[k];
            op[k] = s * __builtin_amdgcn_rcpf(s + d);
        }
        *(float4*)(out + obase + (size_t)r * kNY) = o;
    }
}

extern "C" void kernel_launch(void* const* d_in, const int* in_sizes, int n_in,
                              void* d_out, int out_size, void* d_ws, size_t ws_size,
                              hipStream_t stream) {
    const float* x     = (const float*)d_in[0];
    const float* y     = (const float*)d_in[1];
    const float* sx    = (const float*)d_in[2];
    const float* sy    = (const float*)d_in[3];
    const float* scale = (const float*)d_in[4];
    float* out = (float*)d_out;

    const int nper = kB * kNX;                              // 16384 points/side
    const size_t need = (size_t)2 * nper * sizeof(float2);  // 256 KiB

    if (ws_size >= need) {
        float2* rx = (float2*)d_ws;
        float2* ry = rx + nper;
        row_stats_kernel<<<(2 * nper + 255) / 256, 256, 0, stream>>>(
            x, y, sx, sy, scale, rx, ry, nper);
        const int main_blocks = (kB * kNX * kNY / 32) / 256;  // 8192
        cauchy_main_kernel<<<main_blocks, 256, 0, stream>>>(x, rx, y, ry, out);
    } else {
        const int fb_blocks = (kB * kNX * kNY / 16) / 256;    // 16384
        cauchy_fallback_kernel<<<fb_blocks, 256, 0, stream>>>(
            x, y, sx, sy, scale, out);
    }
}